// Round 18
// baseline (102.610 us; speedup 1.0000x reference)
//
#include <hip/hip_runtime.h>
#include <stdint.h>

// Problem constants (fixed by reference)
#define NB 32    // batch
#define NC 64    // input channels
#define NH 64
#define NW 64
#define NO 512   // output channels
#define ND 256   // dictionary atoms
#define HP 66    // h-padded rows
// xh layout: [NB][66 hp][64 w][64 c] bf16, hp 0/65 zero rows, swizzled:
//   16B chunk (c>>3) of col w stored at chunk slot ((c>>3) ^ (w&7)).

typedef __bf16 bf16x8 __attribute__((ext_vector_type(8)));
typedef short  s16x8  __attribute__((ext_vector_type(8)));
typedef float  f32x4  __attribute__((ext_vector_type(4)));
typedef uint32_t u32x2 __attribute__((ext_vector_type(2)));

__device__ __forceinline__ uint16_t f2bf(float f) {
  uint32_t u = __builtin_bit_cast(uint32_t, f);
  u += 0x7fffu + ((u >> 16) & 1u);   // round-to-nearest-even
  return (uint16_t)(u >> 16);
}
__device__ __forceinline__ uint32_t pk2(float a, float b) {
  return (uint32_t)f2bf(a) | ((uint32_t)f2bf(b) << 16);
}
__device__ __forceinline__ float ubf_lo(uint32_t u) {
  return __builtin_bit_cast(float, u << 16);
}
__device__ __forceinline__ float ubf_hi(uint32_t u) {
  return __builtin_bit_cast(float, u & 0xffff0000u);
}

// async global->LDS, 16B per lane. LDS dest = wave-uniform base + lane*16.
__device__ __forceinline__ void gld16(const uint16_t* g, uint16_t* l) {
  __builtin_amdgcn_global_load_lds(
      (const __attribute__((address_space(1))) void*)(g),
      (__attribute__((address_space(3))) void*)(l), 16, 0, 0);
}

// ---------------- kernel 1: prep (Wd unswizzled + xh transpose) ----------
// bid < ND: Wd[p][d][c] = dict[d][c][p] bf16 (LINEAR — af now loads
//   directly from L2 into registers; no LDS staging, no swizzle needed).
// bid >= ND: x NCHW fp32 -> xh padded swizzled bf16 (verified R13-R16).
__global__ void k_prep(const float* __restrict__ dict,
                       const float* __restrict__ x,
                       uint16_t*    __restrict__ Wd,
                       uint16_t*    __restrict__ xh) {
  const int bid = blockIdx.x;
  const int t = threadIdx.x;            // 256
  if (bid < ND) {                       // ---- Wd build for d = bid ----
    const int d = bid;
#pragma unroll
    for (int j = 0; j < 3; ++j) {
      const int id = t + j * 256;
      if (id < 576) {
        const int c = id & 63, p = id >> 6;
        Wd[(size_t)(p * ND + d) * 64 + c] = f2bf(dict[d * 576 + c * 9 + p]);
      }
    }
    return;
  }
  // ---- nhwc for bh = bid - ND ----
  const int bh = bid - ND;              // b*66 + hp
  const int b = bh / HP, hp = bh % HP;
  uint16_t* row = xh + (size_t)(b * HP + hp) * 4096;
  int4* r4 = reinterpret_cast<int4*>(row);             // 512 int4
  if (hp == 0 || hp == HP - 1) {        // zero h-pad rows
    r4[t]       = int4{0, 0, 0, 0};
    r4[t + 256] = int4{0, 0, 0, 0};
    return;
  }
  __shared__ float tile[64][65];
  const int h = hp - 1;
  const int w = t & 63;
#pragma unroll
  for (int c = (t >> 6); c < 64; c += 4)
    tile[c][w] = x[((size_t)(b * NC + c) * NH + h) * NW + w];
  __syncthreads();
#pragma unroll
  for (int i = 0; i < 2; ++i) {
    const int s = t + i * 256;          // 512 slots: w2 (0..63), cb (0..7)
    const int w2 = s >> 3, cb = s & 7;
    uint32_t dd[4];
#pragma unroll
    for (int j = 0; j < 4; ++j)
      dd[j] = pk2(tile[cb * 8 + 2 * j][w2], tile[cb * 8 + 2 * j + 1][w2]);
    r4[w2 * 8 + (cb ^ (w2 & 7))] =
        int4{(int)dd[0], (int)dd[1], (int)dd[2], (int)dd[3]};
  }
}

// ---------------- kernel 2: dict-conv (af from L2) + combine -------------
// 512 blocks, 512 thr (8 waves). Block = (b, h-quad): 256 pix.
// xs: 6 halo'd xh rows (50.7 KB, staged once). NO as buffer: A-fragments
// load DIRECTLY from the 288-KB L2-resident Wd into registers (each af
// feeds 8 MFMAs; ~0.6 GB L2 traffic chip-wide). P1 is ONE barrier-free
// region per wave: 96 braw ds_reads + 36 af gloads + 288 MFMA.
// S (256 d x 256 pix bf16, 128 KB) overlays xs; P2 gathers verbatim R16.
__global__ __launch_bounds__(512, 2) void k_conv(
    const uint16_t* __restrict__ xh,   // [NB][66][64][64] bf16, pre-swizzled
    const uint16_t* __restrict__ Wd,   // [9][256][64] bf16, LINEAR
    const float*    __restrict__ coef, // [512][4]
    const int*      __restrict__ idx,  // [512][4], values in [0,256)
    const float*    __restrict__ bias, // [512]
    float*          __restrict__ out) {
  __shared__ __align__(16) uint16_t smem[65536];  // 131,072 B
  uint16_t* xs = smem;             // [6][66][64] = 25,344 elems (50,688 B)
  uint8_t*  Sb = (uint8_t*)smem;   // S overlay: 256 rows x 512 B = 128 KB

  const int t = threadIdx.x;
  const int lane = t & 63;
  const int wid  = t >> 6;      // 0..7
  // XCD-chunked: XCD k gets 64 consecutive s (4 b's, L2-resident slice)
  const int flat = blockIdx.x;                 // 512 blocks
  const int s    = (flat & 7) * 64 + (flat >> 3);
  const int b    = s >> 4;
  const int hq   = s & 15;                     // h-quad
  const int h0p  = hq * 4;                     // padded-row base

  // ---- zero the w-halo slots (slot 0 and 65 of each of 6 rows) ----
  if (t < 96) {
    const int r = t >> 4, sl = (t >> 3) & 1, j = t & 7;
    reinterpret_cast<int4*>(xs)[r * 528 + sl * 520 + j] = int4{0, 0, 0, 0};
  }
  // ---- stage xs: 6 rows (hp = h0p..h0p+5), 48 x 1KB chunks ----
  {
#pragma unroll
    for (int j = 0; j < 6; ++j) {
      const int ch = wid * 6 + j;              // 0..47
      const int r = ch >> 3, k = ch & 7;
      gld16(xh + (size_t)(b * HP + h0p + r) * 4096 + k * 512 + lane * 8,
            xs + r * 4224 + 64 + k * 512);
    }
  }

  const int wd  = wid & 3;      // d-tile (64 each)
  const int wn  = wid >> 2;     // pix half (128 each = 2 h-rows)
  const int l15 = lane & 15;
  const int lg  = lane >> 4;

  // per-lane A base in Wd: elem ((tap*256 + wd*64+db*16+l15)*64 + q*32+lg*8)
  const uint16_t* wbase = Wd + (size_t)(wd * 64 + l15) * 64 + lg * 8;

  f32x4 acc[8][4];              // [pix-frag][d-frag]
#pragma unroll
  for (int pb = 0; pb < 8; ++pb)
#pragma unroll
    for (int db = 0; db < 4; ++db)
      acc[pb][db] = (f32x4){0.f, 0.f, 0.f, 0.f};

  __syncthreads();              // xs resident

  // ====== PHASE 1: S = conv(x, dict) — zero barriers, af from L2 ======
#pragma unroll
  for (int g = 0; g < 3; ++g) {
    const int dw = g - 1;
#pragma unroll
    for (int q = 0; q < 2; ++q) {
      const int cbB = (q * 4 + lg) ^ ((l15 + dw) & 7);
      const uint16_t* xb = xs + (l15 + dw + 1) * 64 + cbB * 8;
      bf16x8 braw[4][4];        // rows wn*2+rr, shared across 3 dh taps
#pragma unroll
      for (int rr = 0; rr < 4; ++rr)
#pragma unroll
        for (int nw = 0; nw < 4; ++nw)
          braw[rr][nw] = __builtin_bit_cast(bf16x8,
              *reinterpret_cast<const s16x8*>(
                  xb + (wn * 2 + rr) * 4224 + nw * 1024));
#pragma unroll
      for (int dh = 0; dh < 3; ++dh) {
        const int tap = dh * 3 + g;
        bf16x8 af[4];
#pragma unroll
        for (int db = 0; db < 4; ++db)
          af[db] = __builtin_bit_cast(bf16x8,
              *reinterpret_cast<const s16x8*>(
                  wbase + (size_t)tap * 16384 + db * 1024 + q * 32));
#pragma unroll
        for (int pb = 0; pb < 8; ++pb)
#pragma unroll
          for (int db = 0; db < 4; ++db)
            acc[pb][db] = __builtin_amdgcn_mfma_f32_16x16x32_bf16(
                braw[(pb >> 2) + dh][pb & 3], af[db], acc[pb][db], 0, 0, 0);
      }
    }
  }

  // ---- acc -> S (bf16, XOR-swizzled rows); overlays xs ----
  __syncthreads();              // all phase-1 xs reads complete
#pragma unroll
  for (int pb = 0; pb < 8; ++pb) {
#pragma unroll
    for (int db = 0; db < 4; ++db) {
      const int d   = wd * 64 + db * 16 + l15;
      const int pix = (wn * 2 + (pb >> 2)) * 64 + (pb & 3) * 16 + lg * 4;
      u32x2 u;
      u[0] = pk2(acc[pb][db][0], acc[pb][db][1]);
      u[1] = pk2(acc[pb][db][2], acc[pb][db][3]);
      *reinterpret_cast<u32x2*>(
          Sb + d * 512 + ((pix * 2) ^ ((d & 7) << 4))) = u;
    }
  }
  __syncthreads();              // S fully resident

  // ================= PHASE 2: gather-combine =================
  const int hrow = lane >> 4;          // 0..3 within quad
  const int wcol = (lane & 15) * 4;    // 4 consecutive w per lane
#pragma unroll 4
  for (int oo = 0; oo < 64; ++oo) {
    const int o = wid * 64 + oo;
    const int4 iv = *reinterpret_cast<const int4*>(idx + o * 4);
    const f32x4 cv = *reinterpret_cast<const f32x4*>(coef + o * 4);
    const float bv = bias[o];
    f32x4 v = {bv, bv, bv, bv};
#define GATH(ROW, CS) do {                                                  \
      const int r_ = (ROW);                                                 \
      const u32x2 u_ = *reinterpret_cast<const u32x2*>(                     \
          Sb + r_ * 512 + ((lane * 8) ^ ((r_ & 7) << 4)));                  \
      const float c_ = (CS);                                                \
      v[0] += c_ * ubf_lo(u_[0]);  v[1] += c_ * ubf_hi(u_[0]);              \
      v[2] += c_ * ubf_lo(u_[1]);  v[3] += c_ * ubf_hi(u_[1]);              \
    } while (0)
    GATH(iv.x, cv[0]);
    GATH(iv.y, cv[1]);
    GATH(iv.z, cv[2]);
    GATH(iv.w, cv[3]);
#undef GATH
    float* dst = out + ((size_t)(b * NO + o) * NH + hq * 4 + hrow) * NW + wcol;
    __builtin_nontemporal_store(v, reinterpret_cast<f32x4*>(dst));
  }
}

extern "C" void kernel_launch(void* const* d_in, const int* in_sizes, int n_in,
                              void* d_out, int out_size, void* d_ws, size_t ws_size,
                              hipStream_t stream) {
  const float* x    = (const float*)d_in[0];
  const float* dict = (const float*)d_in[1];
  const float* coef = (const float*)d_in[2];
  const float* bias = (const float*)d_in[3];
  const int*   idx  = (const int*)d_in[4];
  float* out = (float*)d_out;

  // workspace: xh = 32*66*4096*2 B = 16.5 MiB at 0; Wd 288 KiB at +18 MiB
  uint16_t* xh = (uint16_t*)d_ws;
  uint16_t* Wd = (uint16_t*)((char*)d_ws + (18u << 20));

  hipLaunchKernelGGL(k_prep, dim3(ND + NB * HP), dim3(256), 0, stream,
                     dict, x, Wd, xh);
  hipLaunchKernelGGL(k_conv, dim3(512), dim3(512), 0, stream,
                     xh, Wd, coef, idx, bias, out);
}